// Round 5
// baseline (360.503 us; speedup 1.0000x reference)
//
#include <hip/hip_runtime.h>
#include <hip/hip_bf16.h>

typedef __bf16 bf16_t;
typedef __bf16 bf16x4 __attribute__((ext_vector_type(4)));
typedef __bf16 bf16x8 __attribute__((ext_vector_type(8)));
typedef float f32x4 __attribute__((ext_vector_type(4)));

#define ALPHA 8.3f
#define CPAD 72   // bf16 channel stride (144 B, 16B-aligned, conflict-free reads)
#define NCOL 68   // staged cols (64-q tile + halo + align)

// img: [4][64][256][256] f32, depth: [4][1][256][256] f32,
// weight: [64][64][3][3] f32, bias: [1][64] f32, out: [4][64][254][254] f32

// Repack weight -> bf16 A-fragment order [tap(9)][chunk(2)][mblock(4)][lane(64)][j(8)]
//   oc = mblock*16 + (lane&15), c = chunk*32 + (lane>>4)*8 + j
__global__ void repack_w(const float* __restrict__ w, bf16_t* __restrict__ w2) {
    int idx = blockIdx.x * 256 + threadIdx.x;  // 0..36863
    if (idx >= 9 * 2 * 4 * 64 * 8) return;
    int j     = idx & 7;
    int lane  = (idx >> 3) & 63;
    int m     = (idx >> 9) & 3;
    int chunk = (idx >> 11) & 1;
    int tap   = idx >> 12;
    int oc = m * 16 + (lane & 15);
    int c  = chunk * 32 + (lane >> 4) * 8 + j;
    int kt = tap / 3, lt = tap % 3;
    w2[idx] = (bf16_t)w[((oc * 64 + c) * 3 + kt) * 3 + lt];
}

// Block = 256 thr (4 waves) = (2 p-rows) x (2 oc-halves); wave tile 32oc x 64q.
// stage 4 img rows -> 1 barrier -> MFMA compute -> store. TLP (16 waves/CU)
// hides all latency; no persistence, no software pipeline.
__global__ __launch_bounds__(256, 4) void depthconv_mfma(
    const float* __restrict__ img, const float* __restrict__ depth,
    const bf16_t* __restrict__ w2, const float* __restrict__ bias,
    float* __restrict__ out)
{
    __shared__ bf16_t lds[4 * NCOL * CPAD];  // 39,168 B -> 4 blocks/CU

    const int tid = threadIdx.x;
    // blk = ppair*16 + (b*4+qt): each (b,qt) stream stays on one XCD (16%8==0)
    const int blk   = blockIdx.x;
    const int ppair = blk >> 4;
    const int r     = blk & 15;
    const int b     = r >> 2;
    const int qt    = r & 3;
    const int p0    = ppair * 2;
    const int q0    = (qt == 3) ? 190 : qt * 64;  // q 190/191 dup-written identically
    const int s0    = (qt == 3) ? 188 : q0;       // staged col start (float4-aligned)

    const float* imgb = img + (size_t)b * 64 * 65536;
    const float* dep  = depth + (size_t)b * 65536;

    // ---- stage: 4 rows x 68 cols x 64 ch, f32 -> bf16, 4x4 in-register transpose ----
    // unit u = (row, colg, cg): loads 4ch x 4col float4s (L1 merges lines), writes
    // bf16x4 per col (4 accesses/bank: free). 1088 units over 256 threads.
#pragma unroll
    for (int k = 0; k < 5; ++k) {
        int u = tid + (k << 8);
        if (u < 1088) {
            int cg   = u & 15;
            int rest = u >> 4;        // 0..67
            int colg = rest % 17;
            int row  = rest / 17;
            const float* src = imgb + (size_t)(cg * 4) * 65536 + (p0 + row) * 256 + s0 + colg * 4;
            f32x4 v0 = *(const f32x4*)src;
            f32x4 v1 = *(const f32x4*)(src + 65536);
            f32x4 v2 = *(const f32x4*)(src + 2 * 65536);
            f32x4 v3 = *(const f32x4*)(src + 3 * 65536);
            bf16_t* dst = lds + (size_t)(row * NCOL + colg * 4) * CPAD + cg * 4;
#pragma unroll
            for (int i = 0; i < 4; ++i)
                *(bf16x4*)(dst + i * CPAD) =
                    (bf16x4){(bf16_t)v0[i], (bf16_t)v1[i], (bf16_t)v2[i], (bf16_t)v3[i]};
        }
    }
    __syncthreads();

    // ---- compute ----
    const int wv   = tid >> 6;
    const int lane = tid & 63;
    const int pr   = wv >> 1;          // p-row within pair
    const int mh   = wv & 1;           // oc-half (mblocks 2mh, 2mh+1)
    const int n    = lane & 15;
    const int quad = lane >> 4;
    const int prow = p0 + pr;
    const int clb0 = q0 - s0;

    float dc[4];
#pragma unroll
    for (int i = 0; i < 4; ++i)
        dc[i] = dep[(prow + 1) * 256 + q0 + 16 * i + n + 1];

    const f32x4 Z = (f32x4){0.f, 0.f, 0.f, 0.f};
    f32x4 acc[2][4];
#pragma unroll
    for (int mm = 0; mm < 2; ++mm)
#pragma unroll
        for (int i = 0; i < 4; ++i) acc[mm][i] = Z;

    for (int kt = 0; kt < 3; ++kt) {
        float dwv[3][4];
#pragma unroll
        for (int lt = 0; lt < 3; ++lt)
#pragma unroll
            for (int i = 0; i < 4; ++i) {
                float d = dep[(prow + kt) * 256 + q0 + 16 * i + n + lt];
                dwv[lt][i] = __expf(-ALPHA * fabsf(d - dc[i]));
            }
#pragma unroll
        for (int lt = 0; lt < 3; ++lt) {
            const int tap = kt * 3 + lt;
            f32x4 P[2][4];
#pragma unroll
            for (int chunk = 0; chunk < 2; ++chunk) {
                const bf16x8* w2p = (const bf16x8*)w2
                    + ((size_t)((tap * 2 + chunk) * 4 + mh * 2)) * 64 + lane;
                bf16x8 a0 = w2p[0];
                bf16x8 a1 = w2p[64];
#pragma unroll
                for (int i = 0; i < 4; ++i) {
                    const bf16x8 bf = *(const bf16x8*)(
                        lds + (size_t)((pr + kt) * NCOL + clb0 + 16 * i + n + lt) * CPAD
                            + chunk * 32 + quad * 8);
                    if (chunk == 0) {
                        P[0][i] = __builtin_amdgcn_mfma_f32_16x16x32_bf16(a0, bf, Z, 0, 0, 0);
                        P[1][i] = __builtin_amdgcn_mfma_f32_16x16x32_bf16(a1, bf, Z, 0, 0, 0);
                    } else {
                        P[0][i] = __builtin_amdgcn_mfma_f32_16x16x32_bf16(a0, bf, P[0][i], 0, 0, 0);
                        P[1][i] = __builtin_amdgcn_mfma_f32_16x16x32_bf16(a1, bf, P[1][i], 0, 0, 0);
                    }
                }
            }
#pragma unroll
            for (int mm = 0; mm < 2; ++mm)
#pragma unroll
                for (int i = 0; i < 4; ++i)
                    acc[mm][i] += dwv[lt][i] * P[mm][i];
        }
    }

    // epilogue: D[row=quad*4+r2][col=n]; oc = (mh*2+mm)*16 + quad*4 + r2
#pragma unroll
    for (int mm = 0; mm < 2; ++mm) {
#pragma unroll
        for (int r2 = 0; r2 < 4; ++r2) {
            int oc = (mh * 2 + mm) * 16 + quad * 4 + r2;
            float bz = bias[oc];
#pragma unroll
            for (int i = 0; i < 4; ++i) {
                int q = q0 + 16 * i + n;
                out[((size_t)(b * 64 + oc) * 254 + prow) * 254 + q] = acc[mm][i][r2] + bz;
            }
        }
    }
}

extern "C" void kernel_launch(void* const* d_in, const int* in_sizes, int n_in,
                              void* d_out, int out_size, void* d_ws, size_t ws_size,
                              hipStream_t stream) {
    const float* img   = (const float*)d_in[0];
    const float* depth = (const float*)d_in[1];
    const float* w     = (const float*)d_in[2];
    const float* bias  = (const float*)d_in[3];
    bf16_t* w2 = (bf16_t*)d_ws;

    repack_w<<<144, 256, 0, stream>>>(w, w2);
    // 127 p-pairs x 4 b x 4 q-tiles = 2032 blocks, 256 thr (4 waves), 4 blocks/CU
    depthconv_mfma<<<2032, 256, 0, stream>>>(img, depth, w2, bias, (float*)d_out);
}

// Round 6
// 151.035 us; speedup vs baseline: 2.3869x; 2.3869x over previous
//
#include <hip/hip_runtime.h>
#include <hip/hip_bf16.h>

typedef __bf16 bf16_t;
typedef __bf16 bf16x4 __attribute__((ext_vector_type(4)));
typedef __bf16 bf16x8 __attribute__((ext_vector_type(8)));
typedef float f32x4 __attribute__((ext_vector_type(4)));

#define ALPHA 8.3f
#define CPAD 72   // bf16 channel stride (144 B, 16B-aligned, conflict-free reads)
#define NCOL 68   // staged cols (64-q tile + halo + align)

// img: [4][64][256][256] f32, depth: [4][1][256][256] f32,
// weight: [64][64][3][3] f32, bias: [1][64] f32, out: [4][64][254][254] f32

// Repack weight -> bf16 A-fragment order [tap(9)][chunk(2)][mblock(4)][lane(64)][j(8)]
//   oc = mblock*16 + (lane&15), c = chunk*32 + (lane>>4)*8 + j
__global__ void repack_w(const float* __restrict__ w, bf16_t* __restrict__ w2) {
    int idx = blockIdx.x * 256 + threadIdx.x;  // 0..36863
    if (idx >= 9 * 2 * 4 * 64 * 8) return;
    int j     = idx & 7;
    int lane  = (idx >> 3) & 63;
    int m     = (idx >> 9) & 3;
    int chunk = (idx >> 11) & 1;
    int tap   = idx >> 12;
    int oc = m * 16 + (lane & 15);
    int c  = chunk * 32 + (lane >> 4) * 8 + j;
    int kt = tap / 3, lt = tap % 3;
    w2[idx] = (bf16_t)w[((oc * 64 + c) * 3 + kt) * 3 + lt];
}

// Block = 256 thr (4 waves) = (2 p-rows) x (2 oc-halves); wave tile 32oc x 64q.
// stage 4 img rows -> 1 barrier -> MFMA -> store. Latency hidden by TLP.
// NOTE: __launch_bounds__(256,4) made the compiler cap VGPR at 64 -> 655 MB of
// scratch spill traffic (R5: 274 us). (256,2) + ~105-reg live set fits 128 VGPR
// -> 4 waves/SIMD from the HW VGPR rule without forcing a spill.
__global__ __launch_bounds__(256, 2) void depthconv_mfma(
    const float* __restrict__ img, const float* __restrict__ depth,
    const bf16_t* __restrict__ w2, const float* __restrict__ bias,
    float* __restrict__ out)
{
    __shared__ bf16_t lds[4 * NCOL * CPAD];  // 39,168 B -> 4 blocks/CU by LDS

    const int tid = threadIdx.x;
    // blk = ppair*16 + (b*4+qt): each (b,qt) stream stays on one XCD (16%8==0)
    const int blk   = blockIdx.x;
    const int ppair = blk >> 4;
    const int r     = blk & 15;
    const int b     = r >> 2;
    const int qt    = r & 3;
    const int p0    = ppair * 2;
    const int q0    = (qt == 3) ? 190 : qt * 64;  // q 190/191 dup-written identically
    const int s0    = (qt == 3) ? 188 : q0;       // staged col start (float4-aligned)

    const float* imgb = img + (size_t)b * 64 * 65536;
    const float* dep  = depth + (size_t)b * 65536;

    // ---- stage: 4 rows x 68 cols x 64 ch, f32 -> bf16, 4x4 in-register transpose ----
#pragma unroll
    for (int k = 0; k < 5; ++k) {
        int u = tid + (k << 8);
        if (u < 1088) {
            int cg   = u & 15;
            int rest = u >> 4;        // 0..67
            int colg = rest % 17;
            int row  = rest / 17;
            const float* src = imgb + (size_t)(cg * 4) * 65536 + (p0 + row) * 256 + s0 + colg * 4;
            f32x4 v0 = *(const f32x4*)src;
            f32x4 v1 = *(const f32x4*)(src + 65536);
            f32x4 v2 = *(const f32x4*)(src + 2 * 65536);
            f32x4 v3 = *(const f32x4*)(src + 3 * 65536);
            bf16_t* dst = lds + (size_t)(row * NCOL + colg * 4) * CPAD + cg * 4;
#pragma unroll
            for (int i = 0; i < 4; ++i)
                *(bf16x4*)(dst + i * CPAD) =
                    (bf16x4){(bf16_t)v0[i], (bf16_t)v1[i], (bf16_t)v2[i], (bf16_t)v3[i]};
        }
    }
    __syncthreads();

    // ---- compute ----
    const int wv   = tid >> 6;
    const int lane = tid & 63;
    const int pr   = wv >> 1;          // p-row within pair
    const int mh   = wv & 1;           // oc-half (mblocks 2mh, 2mh+1)
    const int n    = lane & 15;
    const int quad = lane >> 4;
    const int prow = p0 + pr;
    const int clb0 = q0 - s0;

    float dc[4];
#pragma unroll
    for (int i = 0; i < 4; ++i)
        dc[i] = dep[(prow + 1) * 256 + q0 + 16 * i + n + 1];

    const f32x4 Z = (f32x4){0.f, 0.f, 0.f, 0.f};
    f32x4 acc[2][4];
#pragma unroll
    for (int mm = 0; mm < 2; ++mm)
#pragma unroll
        for (int i = 0; i < 4; ++i) acc[mm][i] = Z;

    for (int kt = 0; kt < 3; ++kt) {
        float dwv[3][4];
#pragma unroll
        for (int lt = 0; lt < 3; ++lt)
#pragma unroll
            for (int i = 0; i < 4; ++i) {
                float d = dep[(prow + kt) * 256 + q0 + 16 * i + n + lt];
                dwv[lt][i] = __expf(-ALPHA * fabsf(d - dc[i]));
            }
#pragma unroll
        for (int lt = 0; lt < 3; ++lt) {
            const int tap = kt * 3 + lt;
            // hoist all 4 A-fragments of this tap: [chunk][mm], 16 VGPRs
            const bf16x8* w2p = (const bf16x8*)w2 + ((size_t)(tap * 2) * 4 + mh * 2) * 64 + lane;
            bf16x8 a00 = w2p[0];           // chunk0, mm0
            bf16x8 a01 = w2p[64];          // chunk0, mm1
            bf16x8 a10 = w2p[256];         // chunk1, mm0
            bf16x8 a11 = w2p[256 + 64];    // chunk1, mm1
#pragma unroll
            for (int i = 0; i < 4; ++i) {
                const bf16_t* lp = lds
                    + (size_t)((pr + kt) * NCOL + clb0 + 16 * i + n + lt) * CPAD + quad * 8;
                const bf16x8 bf0 = *(const bf16x8*)lp;
                const bf16x8 bf1 = *(const bf16x8*)(lp + 32);
                f32x4 P0 = __builtin_amdgcn_mfma_f32_16x16x32_bf16(a00, bf0, Z, 0, 0, 0);
                f32x4 P1 = __builtin_amdgcn_mfma_f32_16x16x32_bf16(a01, bf0, Z, 0, 0, 0);
                P0 = __builtin_amdgcn_mfma_f32_16x16x32_bf16(a10, bf1, P0, 0, 0, 0);
                P1 = __builtin_amdgcn_mfma_f32_16x16x32_bf16(a11, bf1, P1, 0, 0, 0);
                acc[0][i] += dwv[lt][i] * P0;
                acc[1][i] += dwv[lt][i] * P1;
            }
        }
    }

    // epilogue: D[row=quad*4+r2][col=n]; oc = (mh*2+mm)*16 + quad*4 + r2
#pragma unroll
    for (int mm = 0; mm < 2; ++mm) {
#pragma unroll
        for (int r2 = 0; r2 < 4; ++r2) {
            int oc = (mh * 2 + mm) * 16 + quad * 4 + r2;
            float bz = bias[oc];
#pragma unroll
            for (int i = 0; i < 4; ++i) {
                int q = q0 + 16 * i + n;
                out[((size_t)(b * 64 + oc) * 254 + prow) * 254 + q] = acc[mm][i][r2] + bz;
            }
        }
    }
}

extern "C" void kernel_launch(void* const* d_in, const int* in_sizes, int n_in,
                              void* d_out, int out_size, void* d_ws, size_t ws_size,
                              hipStream_t stream) {
    const float* img   = (const float*)d_in[0];
    const float* depth = (const float*)d_in[1];
    const float* w     = (const float*)d_in[2];
    const float* bias  = (const float*)d_in[3];
    bf16_t* w2 = (bf16_t*)d_ws;

    repack_w<<<144, 256, 0, stream>>>(w, w2);
    // 127 p-pairs x 4 b x 4 q-tiles = 2032 blocks, 256 thr (4 waves)
    depthconv_mfma<<<2032, 256, 0, stream>>>(img, depth, w2, bias, (float*)d_out);
}